// Round 1
// baseline (411.536 us; speedup 1.0000x reference)
//
#include <hip/hip_runtime.h>
#include <math.h>

// ---------------------------------------------------------------------------
// InputEmbedder: depthwise conv stack -> per-(b,t) einsum -> 4x conv1d+GELU
// Sizes: B=2, T=15000, CHNLS=21, HIDDEN=128, Tr=462
// ---------------------------------------------------------------------------

#define NB 2
#define TR 462
#define C5 2688          // HIDDEN*CHNLS
#define WROW 65536       // HIDDEN*512
#define OUTROW 4096      // HIDDEN*32

__device__ __forceinline__ float gelu_exact(float x) {
    return 0.5f * x * (1.0f + erff(x * 0.7071067811865476f));
}

// Generic grouped conv1d (in_per_group = 1), one thread per output element.
// out layout: [B][Cout][Lout] contiguous.
__global__ void dw_conv_kernel(const float* __restrict__ in, const float* __restrict__ wgt,
                               const float* __restrict__ bias, float* __restrict__ out,
                               int Cout, int R, int K, int Lout,
                               long sb, long sc, long st, int total)
{
    int idx = blockIdx.x * blockDim.x + threadIdx.x;
    if (idx >= total) return;
    int to   = idx % Lout;
    int rest = idx / Lout;
    int co   = rest % Cout;
    int b    = rest / Cout;
    int g = co / R;
    const float* ip = in + (long)b * sb + (long)g * sc + (long)(2 * to) * st;
    const float* wp = wgt + co * K;
    float acc = bias[co];
    for (int k = 0; k < K; ++k) acc = fmaf(wp[k], ip[(long)k * st], acc);
    out[idx] = acc;
}

// Stage 5 (K=9), writes TRANSPOSED output [B][Tr][2688] so the fused kernel
// reads emb rows coalesced. Consecutive threads -> consecutive co -> coalesced
// writes.
__global__ void dw_conv5_t_kernel(const float* __restrict__ in, const float* __restrict__ wgt,
                                  const float* __restrict__ bias, float* __restrict__ out)
{
    int idx = blockIdx.x * blockDim.x + threadIdx.x;
    const int total = NB * TR * C5;
    if (idx >= total) return;
    int co = idx % C5;
    int to = (idx / C5) % TR;
    int b  = idx / (C5 * TR);
    int g = co >> 1;                       // R = 2
    const float* ip = in + (long)b * 1252608L + (long)g * 932L + (long)(2 * to);
    const float* wp = wgt + co * 9;
    float acc = bias[co];
#pragma unroll
    for (int k = 0; k < 9; ++k) acc = fmaf(wp[k], ip[k], acc);
    out[idx] = acc;
}

// Gather ch_emb[b][k][j] = ch_table[ch_vector[b][k]][j]
__global__ void gather_che_kernel(const float* __restrict__ table, const int* __restrict__ chv,
                                  float* __restrict__ che)
{
    int idx = blockIdx.x * blockDim.x + threadIdx.x;
    if (idx >= NB * 21 * 512) return;
    int j = idx & 511;
    int k = (idx >> 9) % 21;
    int b = idx / (21 * 512);
    che[idx] = table[chv[b * 21 + k] * 512 + j];
}

// Fused: per (b, t, chunk) compute 256 outputs of the conv/GELU chain.
// Virtual signals per (b,t): w[65536] -> z1[32768] -> g2[16384] -> z3[8192] -> out[4096]
// Chunk of 256 outputs needs (inclusive halos):
//   z3: 2C+2 = 514, g2: 4C+6 = 1030, z1: 8C+14 = 2062, w: 16C+30 = 4126
__global__ __launch_bounds__(256)
void fused_embed_kernel(const float* __restrict__ embT,   // [B][Tr][2688]
                        const float* __restrict__ che,    // [B][21][512]
                        const float* __restrict__ mw1, const float* __restrict__ mb1,
                        const float* __restrict__ mw2, const float* __restrict__ mb2,
                        const float* __restrict__ mw3, const float* __restrict__ mb3,
                        const float* __restrict__ mw4, const float* __restrict__ mb4,
                        float* __restrict__ out)
{
    __shared__ float s_emb[C5];
    __shared__ float s_w[4126];
    __shared__ float s_z1[2062];
    __shared__ float s_g2[1030];
    __shared__ float s_z3[514];

    const int chunk = blockIdx.x;
    const int t     = blockIdx.y;
    const int b     = blockIdx.z;
    const int tid   = threadIdx.x;

    // coalesced emb row load
    const float* erow = embT + ((long)(b * TR + t)) * C5;
    for (int c = tid; c < C5; c += 256) s_emb[c] = erow[c];

    float W1[4], W2[4], W3[4], W4[4];
#pragma unroll
    for (int q = 0; q < 4; ++q) { W1[q] = mw1[q]; W2[q] = mw2[q]; W3[q] = mw3[q]; W4[q] = mw4[q]; }
    const float B1 = mb1[0], B2 = mb2[0], B3 = mb3[0], B4 = mb4[0];
    const float* cheb = che + (long)b * 21 * 512;

    __syncthreads();

    const int P       = chunk * 256;
    const int base_w  = 16 * P - 15;
    const int base_z1 = 8 * P - 7;
    const int base_g2 = 4 * P - 3;
    const int base_z3 = 2 * P - 1;

    // phase 1: w[i*512+j] = sum_k emb[i*21+k] * che[k][j]
    for (int lw = tid; lw < 4126; lw += 256) {
        int g = base_w + lw;
        float v = 0.f;
        if (g >= 0 && g < WROW) {
            int i = g >> 9, j = g & 511;
            const float* e  = s_emb + i * 21;
            const float* cb = cheb + j;
            float acc = 0.f;
#pragma unroll
            for (int k = 0; k < 21; ++k) acc = fmaf(e[k], cb[k * 512], acc);
            v = acc;
        }
        s_w[lw] = v;
    }
    __syncthreads();

    // phase 2: z1 (stride 2, pad 1, K=4)
    for (int lz = tid; lz < 2062; lz += 256) {
        int u = base_z1 + lz;
        float v = 0.f;
        if (u >= 0 && u < 32768) {
            v = B1;
            int g0 = 2 * u - 1;
#pragma unroll
            for (int q = 0; q < 4; ++q) {
                int g = g0 + q;
                float wv = (g >= 0 && g < WROW) ? s_w[g - base_w] : 0.f;
                v = fmaf(W1[q], wv, v);
            }
        }
        s_z1[lz] = v;
    }
    __syncthreads();

    // phase 3: g2 = gelu(conv2(z1))
    for (int lv = tid; lv < 1030; lv += 256) {
        int u = base_g2 + lv;
        float v = 0.f;
        if (u >= 0 && u < 16384) {
            v = B2;
            int g0 = 2 * u - 1;
#pragma unroll
            for (int q = 0; q < 4; ++q) {
                int g = g0 + q;
                float zv = (g >= 0 && g < 32768) ? s_z1[g - base_z1] : 0.f;
                v = fmaf(W2[q], zv, v);
            }
            v = gelu_exact(v);
        }
        s_g2[lv] = v;
    }
    __syncthreads();

    // phase 4: z3
    for (int lz = tid; lz < 514; lz += 256) {
        int u = base_z3 + lz;
        float v = 0.f;
        if (u >= 0 && u < 8192) {
            v = B3;
            int g0 = 2 * u - 1;
#pragma unroll
            for (int q = 0; q < 4; ++q) {
                int g = g0 + q;
                float gv = (g >= 0 && g < 16384) ? s_g2[g - base_g2] : 0.f;
                v = fmaf(W3[q], gv, v);
            }
        }
        s_z3[lz] = v;
    }
    __syncthreads();

    // phase 5: out = gelu(conv4(z3))
    {
        int p = P + tid;
        float v = B4;
        int g0 = 2 * p - 1;
#pragma unroll
        for (int q = 0; q < 4; ++q) {
            int g = g0 + q;
            float zv = (g >= 0 && g < 8192) ? s_z3[g - base_z3] : 0.f;
            v = fmaf(W4[q], zv, v);
        }
        v = gelu_exact(v);
        out[((long)(b * TR + t)) * OUTROW + p] = v;
    }
}

extern "C" void kernel_launch(void* const* d_in, const int* in_sizes, int n_in,
                              void* d_out, int out_size, void* d_ws, size_t ws_size,
                              hipStream_t stream)
{
    const float* x   = (const float*)d_in[0];
    const int*   chv = (const int*)d_in[1];
    const float* w1  = (const float*)d_in[2];  const float* b1 = (const float*)d_in[3];
    const float* w2  = (const float*)d_in[4];  const float* b2 = (const float*)d_in[5];
    const float* w3  = (const float*)d_in[6];  const float* b3 = (const float*)d_in[7];
    const float* w4  = (const float*)d_in[8];  const float* b4 = (const float*)d_in[9];
    const float* w5  = (const float*)d_in[10]; const float* b5 = (const float*)d_in[11];
    const float* tab = (const float*)d_in[12];
    const float* mw1 = (const float*)d_in[13]; const float* mb1 = (const float*)d_in[14];
    const float* mw2 = (const float*)d_in[15]; const float* mb2 = (const float*)d_in[16];
    const float* mw3 = (const float*)d_in[17]; const float* mb3 = (const float*)d_in[18];
    const float* mw4 = (const float*)d_in[19]; const float* mb4 = (const float*)d_in[20];
    float* outp = (float*)d_out;

    float* ws   = (float*)d_ws;
    float* bufA = ws;                 // 2,520,000 floats
    float* bufB = ws + 2520000;       // 2,520,000 floats
    float* che  = ws + 5040000;       // 21,504 floats

    auto launch_dw = [&](const float* in, const float* w, const float* bias, float* out,
                         int Cout, int R, int K, int Lout, long sb, long sc, long st) {
        int total = NB * Cout * Lout;
        dw_conv_kernel<<<(total + 255) / 256, 256, 0, stream>>>(in, w, bias, out,
                                                                Cout, R, K, Lout, sb, sc, st, total);
    };

    // stage 1: x [2][15000][21] viewed as [2][21][15000]; Lout 7497
    launch_dw(x,    w1, b1, bufA, 168,  8, 7, 7497, 315000L,  1L,    21L);
    // stage 2: [2][168][7497] -> [2][336][3746]
    launch_dw(bufA, w2, b2, bufB, 336,  2, 7, 3746, 1259496L, 7497L, 1L);
    // stage 3: -> [2][672][1870]
    launch_dw(bufB, w3, b3, bufA, 672,  2, 7, 1870, 1258656L, 3746L, 1L);
    // stage 4: -> [2][1344][932]
    launch_dw(bufA, w4, b4, bufB, 1344, 2, 7, 932,  1256640L, 1870L, 1L);
    // stage 5 (K=9): -> transposed [2][462][2688]
    {
        int total = NB * TR * C5;
        dw_conv5_t_kernel<<<(total + 255) / 256, 256, 0, stream>>>(bufB, w5, b5, bufA);
    }

    gather_che_kernel<<<(NB * 21 * 512 + 255) / 256, 256, 0, stream>>>(tab, chv, che);

    dim3 grid(16, TR, NB);  // chunk, t, b
    fused_embed_kernel<<<grid, 256, 0, stream>>>(bufA, che,
                                                 mw1, mb1, mw2, mb2, mw3, mb3, mw4, mb4,
                                                 outp);
}

// Round 2
// 352.714 us; speedup vs baseline: 1.1668x; 1.1668x over previous
//
#include <hip/hip_runtime.h>
#include <math.h>

// ---------------------------------------------------------------------------
// InputEmbedder: depthwise conv stack -> per-(b,t) einsum -> 4x conv1d+GELU
// Sizes: B=2, T=15000, CHNLS=21, HIDDEN=128, Tr=462
// ---------------------------------------------------------------------------

#define NB 2
#define TR 462
#define C5 2688          // HIDDEN*CHNLS
#define WROW 65536       // HIDDEN*512
#define OUTROW 4096      // HIDDEN*32

__device__ __forceinline__ float gelu_exact(float x) {
    return 0.5f * x * (1.0f + erff(x * 0.7071067811865476f));
}

// Transpose x [B][15000][21] -> xT [B][21][15000], coalesced both sides.
// LDS row stride 257 (odd) -> conflict-free.
__global__ void transpose_x_kernel(const float* __restrict__ in, float* __restrict__ out)
{
    __shared__ float s[21 * 257];
    const int b   = blockIdx.y;
    const int t0  = blockIdx.x * 256;
    const int tid = threadIdx.x;
    const float* src = in + (long)b * 315000L + (long)t0 * 21L;
    const int limit = 315000 - t0 * 21;
#pragma unroll
    for (int j = 0; j < 21; ++j) {
        int f = tid + j * 256;
        if (f < limit) {
            int t = f / 21, c = f - t * 21;
            s[c * 257 + t] = src[f];
        }
    }
    __syncthreads();
    float* dst = out + (long)b * 315000L + t0;
    if (t0 + tid < 15000) {
#pragma unroll
        for (int c = 0; c < 21; ++c)
            dst[c * 15000 + tid] = s[c * 257 + tid];
    }
}

// Generic grouped conv1d (in_per_group = 1), one thread per output element.
// out layout: [B][Cout][Lout] contiguous.
__global__ void dw_conv_kernel(const float* __restrict__ in, const float* __restrict__ wgt,
                               const float* __restrict__ bias, float* __restrict__ out,
                               int Cout, int R, int K, int Lout,
                               long sb, long sc, int total)
{
    int idx = blockIdx.x * blockDim.x + threadIdx.x;
    if (idx >= total) return;
    int to   = idx % Lout;
    int rest = idx / Lout;
    int co   = rest % Cout;
    int b    = rest / Cout;
    int g = co / R;
    const float* ip = in + (long)b * sb + (long)g * sc + (long)(2 * to);
    const float* wp = wgt + co * K;
    float acc = bias[co];
    for (int k = 0; k < K; ++k) acc = fmaf(wp[k], ip[k], acc);
    out[idx] = acc;
}

// Stage 5 (K=9), writes TRANSPOSED output [B][Tr][2688].
__global__ void dw_conv5_t_kernel(const float* __restrict__ in, const float* __restrict__ wgt,
                                  const float* __restrict__ bias, float* __restrict__ out)
{
    int idx = blockIdx.x * blockDim.x + threadIdx.x;
    const int total = NB * TR * C5;
    if (idx >= total) return;
    int co = idx % C5;
    int to = (idx / C5) % TR;
    int b  = idx / (C5 * TR);
    int g = co >> 1;                       // R = 2
    const float* ip = in + (long)b * 1252608L + (long)g * 932L + (long)(2 * to);
    const float* wp = wgt + co * 9;
    float acc = bias[co];
#pragma unroll
    for (int k = 0; k < 9; ++k) acc = fmaf(wp[k], ip[k], acc);
    out[idx] = acc;
}

// Gather ch_emb[b][k][j] = ch_table[ch_vector[b][k]][j]
__global__ void gather_che_kernel(const float* __restrict__ table, const int* __restrict__ chv,
                                  float* __restrict__ che)
{
    int idx = blockIdx.x * blockDim.x + threadIdx.x;
    if (idx >= NB * 21 * 512) return;
    int j = idx & 511;
    int k = (idx >> 9) % 21;
    int b = idx / (21 * 512);
    che[idx] = table[chv[b * 21 + k] * 512 + j];
}

// Fused: per (b, t, chunk) compute 256 outputs of the conv/GELU chain.
// Virtual signals per (b,t): w[65536] -> z1[32768] -> g2[16384] -> z3[8192] -> out[4096]
// s_w holds 10 FULL 512-wide w-rows starting at i0 = max(0, 8*chunk-1):
//   covers w indices [i0*512, i0*512+5120) supseteq [16P-15, 16P+4111) for all chunks.
__global__ __launch_bounds__(256)
void fused_embed_kernel(const float* __restrict__ embT,   // [B][Tr][2688]
                        const float* __restrict__ che,    // [B][21][512]
                        const float* __restrict__ mw1, const float* __restrict__ mb1,
                        const float* __restrict__ mw2, const float* __restrict__ mb2,
                        const float* __restrict__ mw3, const float* __restrict__ mb3,
                        const float* __restrict__ mw4, const float* __restrict__ mb4,
                        float* __restrict__ out)
{
    __shared__ float s_emb[C5];
    __shared__ float s_w[5120];
    __shared__ float s_z1[2062];
    __shared__ float s_g2[1030];
    __shared__ float s_z3[514];

    const int chunk = blockIdx.x;
    const int t     = blockIdx.y;
    const int b     = blockIdx.z;
    const int tid   = threadIdx.x;

    // coalesced emb row load
    const float* erow = embT + ((long)(b * TR + t)) * C5;
    for (int c = tid; c < C5; c += 256) s_emb[c] = erow[c];

    float W1[4], W2[4], W3[4], W4[4];
#pragma unroll
    for (int q = 0; q < 4; ++q) { W1[q] = mw1[q]; W2[q] = mw2[q]; W3[q] = mw3[q]; W4[q] = mw4[q]; }
    const float B1 = mb1[0], B2 = mb2[0], B3 = mb3[0], B4 = mb4[0];
    const float* cheb = che + (long)b * 10752;

    const int i0      = (chunk == 0) ? 0 : 8 * chunk - 1;
    const int base_sw = i0 * 512;

    // prefetch first che column into registers (independent of s_emb)
    float cr0[21];
#pragma unroll
    for (int k = 0; k < 21; ++k) cr0[k] = cheb[k * 512 + tid];

    __syncthreads();

    // ---- phase 1: w rows i0..i0+9, thread owns columns tid and tid+256 ----
    {
#pragma unroll
        for (int r = 0; r < 10; ++r) {
            const float* e = s_emb + (((i0 + r) < 128) ? (i0 + r) : 127) * 21;  // clamp; clamped rows never read
            float acc = 0.f;
#pragma unroll
            for (int k = 0; k < 21; ++k) acc = fmaf(e[k], cr0[k], acc);
            s_w[r * 512 + tid] = acc;
        }
        float cr1[21];
#pragma unroll
        for (int k = 0; k < 21; ++k) cr1[k] = cheb[k * 512 + 256 + tid];
#pragma unroll
        for (int r = 0; r < 10; ++r) {
            const float* e = s_emb + (((i0 + r) < 128) ? (i0 + r) : 127) * 21;
            float acc = 0.f;
#pragma unroll
            for (int k = 0; k < 21; ++k) acc = fmaf(e[k], cr1[k], acc);
            s_w[r * 512 + 256 + tid] = acc;
        }
    }
    __syncthreads();

    const int P       = chunk * 256;
    const int base_z1 = 8 * P - 7;
    const int base_g2 = 4 * P - 3;
    const int base_z3 = 2 * P - 1;

    // phase 2: z1 (stride 2, pad 1, K=4)
    for (int lz = tid; lz < 2062; lz += 256) {
        int u = base_z1 + lz;
        float v = 0.f;
        if (u >= 0 && u < 32768) {
            v = B1;
            int g0 = 2 * u - 1;
#pragma unroll
            for (int q = 0; q < 4; ++q) {
                int g = g0 + q;
                float wv = (g >= 0 && g < WROW) ? s_w[g - base_sw] : 0.f;
                v = fmaf(W1[q], wv, v);
            }
        }
        s_z1[lz] = v;
    }
    __syncthreads();

    // phase 3: g2 = gelu(conv2(z1))
    for (int lv = tid; lv < 1030; lv += 256) {
        int u = base_g2 + lv;
        float v = 0.f;
        if (u >= 0 && u < 16384) {
            v = B2;
            int g0 = 2 * u - 1;
#pragma unroll
            for (int q = 0; q < 4; ++q) {
                int g = g0 + q;
                float zv = (g >= 0 && g < 32768) ? s_z1[g - base_z1] : 0.f;
                v = fmaf(W2[q], zv, v);
            }
            v = gelu_exact(v);
        }
        s_g2[lv] = v;
    }
    __syncthreads();

    // phase 4: z3
    for (int lz = tid; lz < 514; lz += 256) {
        int u = base_z3 + lz;
        float v = 0.f;
        if (u >= 0 && u < 8192) {
            v = B3;
            int g0 = 2 * u - 1;
#pragma unroll
            for (int q = 0; q < 4; ++q) {
                int g = g0 + q;
                float gv = (g >= 0 && g < 16384) ? s_g2[g - base_g2] : 0.f;
                v = fmaf(W3[q], gv, v);
            }
        }
        s_z3[lz] = v;
    }
    __syncthreads();

    // phase 5: out = gelu(conv4(z3))
    {
        int p = P + tid;
        float v = B4;
        int g0 = 2 * p - 1;
#pragma unroll
        for (int q = 0; q < 4; ++q) {
            int g = g0 + q;
            float zv = (g >= 0 && g < 8192) ? s_z3[g - base_z3] : 0.f;
            v = fmaf(W4[q], zv, v);
        }
        v = gelu_exact(v);
        out[((long)(b * TR + t)) * OUTROW + p] = v;
    }
}

extern "C" void kernel_launch(void* const* d_in, const int* in_sizes, int n_in,
                              void* d_out, int out_size, void* d_ws, size_t ws_size,
                              hipStream_t stream)
{
    const float* x   = (const float*)d_in[0];
    const int*   chv = (const int*)d_in[1];
    const float* w1  = (const float*)d_in[2];  const float* b1 = (const float*)d_in[3];
    const float* w2  = (const float*)d_in[4];  const float* b2 = (const float*)d_in[5];
    const float* w3  = (const float*)d_in[6];  const float* b3 = (const float*)d_in[7];
    const float* w4  = (const float*)d_in[8];  const float* b4 = (const float*)d_in[9];
    const float* w5  = (const float*)d_in[10]; const float* b5 = (const float*)d_in[11];
    const float* tab = (const float*)d_in[12];
    const float* mw1 = (const float*)d_in[13]; const float* mb1 = (const float*)d_in[14];
    const float* mw2 = (const float*)d_in[15]; const float* mb2 = (const float*)d_in[16];
    const float* mw3 = (const float*)d_in[17]; const float* mb3 = (const float*)d_in[18];
    const float* mw4 = (const float*)d_in[19]; const float* mb4 = (const float*)d_in[20];
    float* outp = (float*)d_out;

    float* ws   = (float*)d_ws;
    float* bufA = ws;                 // 2,520,000 floats
    float* bufB = ws + 2520000;       // 2,520,000 floats (also holds xT transiently)
    float* che  = ws + 5040000;       // 21,504 floats

    // transpose x into bufB (dead after stage 1)
    {
        dim3 grid((15000 + 255) / 256, NB);
        transpose_x_kernel<<<grid, 256, 0, stream>>>(x, bufB);
    }

    auto launch_dw = [&](const float* in, const float* w, const float* bias, float* out,
                         int Cout, int R, int K, int Lout, long sb, long sc) {
        int total = NB * Cout * Lout;
        dw_conv_kernel<<<(total + 255) / 256, 256, 0, stream>>>(in, w, bias, out,
                                                                Cout, R, K, Lout, sb, sc, total);
    };

    // stage 1: xT [2][21][15000] -> [2][168][7497]
    launch_dw(bufB, w1, b1, bufA, 168,  8, 7, 7497, 315000L,  15000L);
    // stage 2: [2][168][7497] -> [2][336][3746]
    launch_dw(bufA, w2, b2, bufB, 336,  2, 7, 3746, 1259496L, 7497L);
    // stage 3: -> [2][672][1870]
    launch_dw(bufB, w3, b3, bufA, 672,  2, 7, 1870, 1258656L, 3746L);
    // stage 4: -> [2][1344][932]
    launch_dw(bufA, w4, b4, bufB, 1344, 2, 7, 932,  1256640L, 1870L);
    // stage 5 (K=9): -> transposed [2][462][2688]
    {
        int total = NB * TR * C5;
        dw_conv5_t_kernel<<<(total + 255) / 256, 256, 0, stream>>>(bufB, w5, b5, bufA);
    }

    gather_che_kernel<<<(NB * 21 * 512 + 255) / 256, 256, 0, stream>>>(tab, chv, che);

    dim3 grid(16, TR, NB);  // chunk, t, b
    fused_embed_kernel<<<grid, 256, 0, stream>>>(bufA, che,
                                                 mw1, mb1, mw2, mb2, mw3, mb3, mw4, mb4,
                                                 outp);
}

// Round 3
// 160.841 us; speedup vs baseline: 2.5587x; 2.1929x over previous
//
#include <hip/hip_runtime.h>
#include <math.h>

// ---------------------------------------------------------------------------
// InputEmbedder: depthwise conv stack -> per-(b,t) einsum -> 4x conv1d+GELU
// Sizes: B=2, T=15000, CHNLS=21, HIDDEN=128, Tr=462
//
// Key algebra: conv1∘conv2 (both stride2,K4,pad1) == one stride4,K10 conv c2;
// pushed through the einsum:  z2[i*128+m] = Bc + sum_k emb[i*21+k]*cheC[k][m]
// for interior m, where cheC[k][m] = sum_r c2[r]*che[k][4m-3+r].
// Boundary m=0/127 need a neighbor-row correction (cheL/cheN), global u=0 and
// u=16383 need extra scalar corrections (z1 zero-padding differs).
// Same composition for conv3∘conv4 = c4 applied to gelu(z2).
// ---------------------------------------------------------------------------

#define NB 2
#define TR 462
#define C5 2688          // HIDDEN*CHNLS
#define OUTROW 4096      // HIDDEN*32

__device__ __forceinline__ float gelu_exact(float x) {
    return 0.5f * x * (1.0f + erff(x * 0.7071067811865476f));
}

// c[r] = sum_{2p+q=r, p,q in [0,4)} A[p]*B[q]
__device__ __forceinline__ void composite10(const float* A, const float* Bv, float* c) {
#pragma unroll
    for (int r = 0; r < 10; ++r) {
        float acc = 0.f;
#pragma unroll
        for (int p = 0; p < 4; ++p) {
            int q = r - 2 * p;
            if (q >= 0 && q < 4) acc = fmaf(A[p], Bv[q], acc);
        }
        c[r] = acc;
    }
}

// Transpose x [B][15000][21] -> xT [B][21][15000]
__global__ void transpose_x_kernel(const float* __restrict__ in, float* __restrict__ out)
{
    __shared__ float s[21 * 257];
    const int b   = blockIdx.y;
    const int t0  = blockIdx.x * 256;
    const int tid = threadIdx.x;
    const float* src = in + (long)b * 315000L + (long)t0 * 21L;
    const int limit = 315000 - t0 * 21;
#pragma unroll
    for (int j = 0; j < 21; ++j) {
        int f = tid + j * 256;
        if (f < limit) {
            int t = f / 21, c = f - t * 21;
            s[c * 257 + t] = src[f];
        }
    }
    __syncthreads();
    float* dst = out + (long)b * 315000L + t0;
    if (t0 + tid < 15000) {
#pragma unroll
        for (int c = 0; c < 21; ++c)
            dst[c * 15000 + tid] = s[c * 257 + tid];
    }
}

// Generic grouped conv1d (in_per_group = 1), one thread per output element.
__global__ void dw_conv_kernel(const float* __restrict__ in, const float* __restrict__ wgt,
                               const float* __restrict__ bias, float* __restrict__ out,
                               int Cout, int R, int K, int Lout,
                               long sb, long sc, int total)
{
    int idx = blockIdx.x * blockDim.x + threadIdx.x;
    if (idx >= total) return;
    int to   = idx % Lout;
    int rest = idx / Lout;
    int co   = rest % Cout;
    int b    = rest / Cout;
    int g = co / R;
    const float* ip = in + (long)b * sb + (long)g * sc + (long)(2 * to);
    const float* wp = wgt + co * K;
    float acc = bias[co];
    for (int k = 0; k < K; ++k) acc = fmaf(wp[k], ip[k], acc);
    out[idx] = acc;
}

// Stage 5 (K=9), writes TRANSPOSED output [B][Tr][2688].
__global__ void dw_conv5_t_kernel(const float* __restrict__ in, const float* __restrict__ wgt,
                                  const float* __restrict__ bias, float* __restrict__ out)
{
    int idx = blockIdx.x * blockDim.x + threadIdx.x;
    const int total = NB * TR * C5;
    if (idx >= total) return;
    int co = idx % C5;
    int to = (idx / C5) % TR;
    int b  = idx / (C5 * TR);
    int g = co >> 1;                       // R = 2
    const float* ip = in + (long)b * 1252608L + (long)g * 932L + (long)(2 * to);
    const float* wp = wgt + co * 9;
    float acc = bias[co];
#pragma unroll
    for (int k = 0; k < 9; ++k) acc = fmaf(wp[k], ip[k], acc);
    out[idx] = acc;
}

// Gather ch_emb[b][k][j] = ch_table[ch_vector[b][k]][j]
__global__ void gather_che_kernel(const float* __restrict__ table, const int* __restrict__ chv,
                                  float* __restrict__ che)
{
    int idx = blockIdx.x * blockDim.x + threadIdx.x;
    if (idx >= NB * 21 * 512) return;
    int j = idx & 511;
    int k = (idx >> 9) % 21;
    int b = idx / (21 * 512);
    che[idx] = table[chv[b * 21 + k] * 512 + j];
}

// Precompute cheC[b][k][m] (m=0 slot holds cheM, m=127 holds cheR) and
// cheLN[b][{L,N}][k].
__global__ void chec_kernel(const float* __restrict__ che,
                            const float* __restrict__ mw1, const float* __restrict__ mw2,
                            float* __restrict__ cheC, float* __restrict__ cheLN)
{
    const int b = blockIdx.x;
    const int m = threadIdx.x;   // 0..127
    float W1[4], W2[4], c2[10];
#pragma unroll
    for (int q = 0; q < 4; ++q) { W1[q] = mw1[q]; W2[q] = mw2[q]; }
    composite10(W2, W1, c2);
    const float* cb = che + b * 21 * 512;
    float* cc = cheC + b * 21 * 128;
    for (int k = 0; k < 21; ++k) {
        float acc = 0.f;
        if (m == 0) {
#pragma unroll
            for (int r = 3; r < 10; ++r) acc = fmaf(c2[r], cb[k * 512 + r - 3], acc);
        } else if (m == 127) {
#pragma unroll
            for (int r = 0; r < 7; ++r) acc = fmaf(c2[r], cb[k * 512 + 505 + r], acc);
        } else {
            int j0 = 4 * m - 3;
#pragma unroll
            for (int r = 0; r < 10; ++r) acc = fmaf(c2[r], cb[k * 512 + j0 + r], acc);
        }
        cc[k * 128 + m] = acc;
    }
    if (m < 21) {
        int k = m;
        float l = 0.f, n = 0.f;
#pragma unroll
        for (int r = 0; r < 3; ++r)  l = fmaf(c2[r], cb[k * 512 + 509 + r], l);
#pragma unroll
        for (int r = 7; r < 10; ++r) n = fmaf(c2[r], cb[k * 512 + r - 7], n);
        cheLN[b * 42 + k]      = l;
        cheLN[b * 42 + 21 + k] = n;
    }
}

// Fused einsum+conv-chain. One block per (b, t, half). half h covers g2 rows
// [63h, 63h+64] (65 rows, 1-row overlap) and output p in [2048h, 2048h+2048).
// s_g2 slot layout: slot = 4 + (u - 8064*half); slots 0..3 and 8324.. zero-pad.
__global__ __launch_bounds__(256)
void fused_embed_kernel(const float* __restrict__ embT,   // [B][Tr][2688]
                        const float* __restrict__ cheC,   // [B][21][128]
                        const float* __restrict__ cheLN,  // [B][2][21]
                        const float* __restrict__ che,    // [B][21][512]
                        const float* __restrict__ mw1, const float* __restrict__ mb1,
                        const float* __restrict__ mw2, const float* __restrict__ mb2,
                        const float* __restrict__ mw3, const float* __restrict__ mb3,
                        const float* __restrict__ mw4, const float* __restrict__ mb4,
                        float* __restrict__ out)
{
    __shared__ float s_g2[8336];

    const int half = blockIdx.x;
    const int t    = blockIdx.y;
    const int b    = blockIdx.z;
    const int tid  = threadIdx.x;
    const int m    = tid & 127;
    const int h    = tid >> 7;
    const int ibase = half * 63;

    // zero the pad slots (0..3 low, 8324..8335 high)
    if (tid < 16) s_g2[(tid < 4) ? tid : (8320 + tid)] = 0.f;

    float W1[4], W2[4], W3[4], W4[4];
#pragma unroll
    for (int q = 0; q < 4; ++q) { W1[q] = mw1[q]; W2[q] = mw2[q]; W3[q] = mw3[q]; W4[q] = mw4[q]; }
    const float B1 = mb1[0], B2 = mb2[0], B3 = mb3[0], B4 = mb4[0];
    const float Bc = B2 + B1 * (W2[0] + W2[1] + W2[2] + W2[3]);

    // per-thread cheC column (register-resident)
    const float* ccp = cheC + b * 2688 + m;
    float cc[21];
#pragma unroll
    for (int k = 0; k < 21; ++k) cc[k] = ccp[k * 128];

    const float* ebase = embT + ((long)(b * TR + t)) * C5;

    // ---- phase A: z2 rows via emb (scalar path) x cheC (registers) ----
    const int s0 = h ? 33 : 0;
    const int s1 = h ? 65 : 33;
#pragma unroll 2
    for (int s = s0; s < s1; ++s) {
        int i = __builtin_amdgcn_readfirstlane(ibase + s);
        const float* er = ebase + i * 21;
        float z = Bc;
#pragma unroll
        for (int k = 0; k < 21; ++k) z = fmaf(er[k], cc[k], z);
        float gz = gelu_exact(z);
        bool bnd = (m == 0) || (m == 127);
        s_g2[4 + s * 128 + m] = bnd ? z : gz;   // boundary slots: raw z2, fixed in A2
    }
    __syncthreads();

    // ---- phase A2: boundary-column corrections, then gelu those slots ----
    if (tid < 130) {
        const int ir   = tid >> 1;
        const int side = tid & 1;     // 0: m=0, 1: m=127
        const int i    = ibase + ir;
        const int slot = 4 + ir * 128 + (side ? 127 : 0);
        float corr = 0.f;
        if (side == 0) {
            if (i == 0) {
                float w0 = 0.f;
                const float* cb = che + b * 21 * 512;
#pragma unroll
                for (int k = 0; k < 21; ++k) w0 = fmaf(ebase[k], cb[k * 512], w0);
                corr = -W2[0] * (B1 + W1[3] * w0);
            } else {
                const float* ep = ebase + (i - 1) * 21;
                const float* cl = cheLN + b * 42;
#pragma unroll
                for (int k = 0; k < 21; ++k) corr = fmaf(ep[k], cl[k], corr);
            }
        } else {
            if (i == 127) {
                float wl = 0.f;
                const float* cb = che + b * 21 * 512 + 511;
                const float* ep = ebase + 127 * 21;
#pragma unroll
                for (int k = 0; k < 21; ++k) wl = fmaf(ep[k], cb[k * 512], wl);
                corr = -W2[3] * (B1 + W1[0] * wl);
            } else {
                const float* ep = ebase + (i + 1) * 21;
                const float* cn = cheLN + b * 42 + 21;
#pragma unroll
                for (int k = 0; k < 21; ++k) corr = fmaf(ep[k], cn[k], corr);
            }
        }
        s_g2[slot] = gelu_exact(s_g2[slot] + corr);
    }
    __syncthreads();

    // ---- phase B: composite conv3∘conv4 over gelu'd g2, gelu, store ----
    float c4[10];
    composite10(W4, W3, c4);
    const float Bc2 = B4 + B3 * (W4[0] + W4[1] + W4[2] + W4[3]);
    float* orow = out + ((long)(b * TR + t)) * OUTROW;
#pragma unroll
    for (int s = 0; s < 8; ++s) {
        const int p    = half * 2048 + tid + 256 * s;
        const int idx0 = 4 * p - (half ? 8064 : 0);   // 16B-aligned
        const float4 v0 = *(const float4*)&s_g2[idx0];
        const float4 v1 = *(const float4*)&s_g2[idx0 + 4];
        const float4 v2 = *(const float4*)&s_g2[idx0 + 8];
        const float buf[12] = { v0.x, v0.y, v0.z, v0.w,
                                v1.x, v1.y, v1.z, v1.w,
                                v2.x, v2.y, v2.z, v2.w };
        float z = Bc2;
#pragma unroll
        for (int r = 0; r < 10; ++r) z = fmaf(c4[r], buf[r + 1], z);
        if (p == 0)    z -= W4[0] * (B3 + W3[3] * s_g2[4]);
        if (p == 4095) z -= W4[3] * (B3 + W3[0] * s_g2[8323]);
        orow[p] = gelu_exact(z);
    }
}

extern "C" void kernel_launch(void* const* d_in, const int* in_sizes, int n_in,
                              void* d_out, int out_size, void* d_ws, size_t ws_size,
                              hipStream_t stream)
{
    const float* x   = (const float*)d_in[0];
    const int*   chv = (const int*)d_in[1];
    const float* w1  = (const float*)d_in[2];  const float* b1 = (const float*)d_in[3];
    const float* w2  = (const float*)d_in[4];  const float* b2 = (const float*)d_in[5];
    const float* w3  = (const float*)d_in[6];  const float* b3 = (const float*)d_in[7];
    const float* w4  = (const float*)d_in[8];  const float* b4 = (const float*)d_in[9];
    const float* w5  = (const float*)d_in[10]; const float* b5 = (const float*)d_in[11];
    const float* tab = (const float*)d_in[12];
    const float* mw1 = (const float*)d_in[13]; const float* mb1 = (const float*)d_in[14];
    const float* mw2 = (const float*)d_in[15]; const float* mb2 = (const float*)d_in[16];
    const float* mw3 = (const float*)d_in[17]; const float* mb3 = (const float*)d_in[18];
    const float* mw4 = (const float*)d_in[19]; const float* mb4 = (const float*)d_in[20];
    float* outp = (float*)d_out;

    float* ws    = (float*)d_ws;
    float* bufA  = ws;                 // 2,520,000 floats
    float* bufB  = ws + 2520000;       // 2,520,000 floats (xT transiently)
    float* che   = ws + 5040000;       // 21,504 floats
    float* cheC  = ws + 5061504;       // 5,376 floats
    float* cheLN = ws + 5066880;       // 84 floats

    // transpose x into bufB (dead after stage 1)
    {
        dim3 grid((15000 + 255) / 256, NB);
        transpose_x_kernel<<<grid, 256, 0, stream>>>(x, bufB);
    }

    auto launch_dw = [&](const float* in, const float* w, const float* bias, float* out,
                         int Cout, int R, int K, int Lout, long sb, long sc) {
        int total = NB * Cout * Lout;
        dw_conv_kernel<<<(total + 255) / 256, 256, 0, stream>>>(in, w, bias, out,
                                                                Cout, R, K, Lout, sb, sc, total);
    };

    // stage 1: xT [2][21][15000] -> [2][168][7497]
    launch_dw(bufB, w1, b1, bufA, 168,  8, 7, 7497, 315000L,  15000L);
    // stage 2: -> [2][336][3746]
    launch_dw(bufA, w2, b2, bufB, 336,  2, 7, 3746, 1259496L, 7497L);
    // stage 3: -> [2][672][1870]
    launch_dw(bufB, w3, b3, bufA, 672,  2, 7, 1870, 1258656L, 3746L);
    // stage 4: -> [2][1344][932]
    launch_dw(bufA, w4, b4, bufB, 1344, 2, 7, 932,  1256640L, 1870L);
    // stage 5 (K=9): -> transposed [2][462][2688]
    {
        int total = NB * TR * C5;
        dw_conv5_t_kernel<<<(total + 255) / 256, 256, 0, stream>>>(bufB, w5, b5, bufA);
    }

    gather_che_kernel<<<(NB * 21 * 512 + 255) / 256, 256, 0, stream>>>(tab, chv, che);
    chec_kernel<<<NB, 128, 0, stream>>>(che, mw1, mw2, cheC, cheLN);

    dim3 grid(2, TR, NB);  // half, t, b
    fused_embed_kernel<<<grid, 256, 0, stream>>>(bufA, cheC, cheLN, che,
                                                 mw1, mb1, mw2, mb2, mw3, mb3, mw4, mb4,
                                                 outp);
}

// Round 4
// 95.232 us; speedup vs baseline: 4.3214x; 1.6889x over previous
//
#include <hip/hip_runtime.h>
#include <math.h>

// ---------------------------------------------------------------------------
// InputEmbedder: depthwise conv stack -> per-(b,t) einsum -> 4x conv1d+GELU
// Sizes: B=2, T=15000, CHNLS=21, HIDDEN=128, Tr=462
//
// R4: entire 5-stage depthwise stack fused into ONE kernel (per (b, c, tile)
// block, all intermediates in LDS; no padding anywhere so tiles are exact).
// Einsum+tail-conv algebra unchanged from R3 (composite stride-4 K=10 convs
// pushed through the einsum via cheC).
// ---------------------------------------------------------------------------

#define NB 2
#define TR 462
#define C5 2688          // HIDDEN*CHNLS
#define OUTROW 4096      // HIDDEN*32

// conv-stack tiling: 11 tiles of T5=42 stage-5 outputs (462 = 11*42)
#define T5  42
#define L0T 1531         // x tile len       = 2*L1T+5
#define L1T 763          // s1 len per ch    = 2*L2T+5
#define L2T 379          // s2               = 2*L3T+5
#define L3T 187          // s3               = 2*L4T+5
#define L4T 91           // s4               = 2*T5+7
#define SS1 768          // channel strides (>= 2*p_last+12 for b128 pair reads)
#define SS2 384
#define SS3 192
#define SS4 93           // odd -> stage-5 cross-channel reads conflict-free

__device__ __forceinline__ float gelu_exact(float x) {
    return 0.5f * x * (1.0f + erff(x * 0.7071067811865476f));
}

// c[r] = sum_{2p+q=r, p,q in [0,4)} A[p]*B[q]
__device__ __forceinline__ void composite10(const float* A, const float* Bv, float* c) {
#pragma unroll
    for (int r = 0; r < 10; ++r) {
        float acc = 0.f;
#pragma unroll
        for (int p = 0; p < 4; ++p) {
            int q = r - 2 * p;
            if (q >= 0 && q < 4) acc = fmaf(A[p], Bv[q], acc);
        }
        c[r] = acc;
    }
}

// Transpose x [B][15000][21] -> xT [B][21][15000]
__global__ void transpose_x_kernel(const float* __restrict__ in, float* __restrict__ out)
{
    __shared__ float s[21 * 257];
    const int b   = blockIdx.y;
    const int t0  = blockIdx.x * 256;
    const int tid = threadIdx.x;
    const float* src = in + (long)b * 315000L + (long)t0 * 21L;
    const int limit = 315000 - t0 * 21;
#pragma unroll
    for (int j = 0; j < 21; ++j) {
        int f = tid + j * 256;
        if (f < limit) {
            int t = f / 21, c = f - t * 21;
            s[c * 257 + t] = src[f];
        }
    }
    __syncthreads();
    float* dst = out + (long)b * 315000L + t0;
    if (t0 + tid < 15000) {
#pragma unroll
        for (int c = 0; c < 21; ++c)
            dst[c * 15000 + tid] = s[c * 257 + tid];
    }
}

// All 5 depthwise stages for one (b, orig-channel c, time tile) in LDS.
__global__ __launch_bounds__(256)
void conv_stack_kernel(const float* __restrict__ xT,
                       const float* __restrict__ w1, const float* __restrict__ b1,
                       const float* __restrict__ w2, const float* __restrict__ b2,
                       const float* __restrict__ w3, const float* __restrict__ b3,
                       const float* __restrict__ w4, const float* __restrict__ b4,
                       const float* __restrict__ w5, const float* __restrict__ b5,
                       float* __restrict__ embT)
{
    __shared__ __align__(16) float A[6144];   // x(1531) -> s2(16x384) -> s4(64x93)
    __shared__ __align__(16) float B[6144];   // s1(8x768) -> s3(32x192)
    const int tile = blockIdx.x;
    const int c    = blockIdx.y;
    const int b    = blockIdx.z;
    const int tid  = threadIdx.x;
    const int lane = tid & 63;
    const int wq   = tid >> 6;        // 0..3
    const int t0   = tile * T5;

    // ---- load x tile (coalesced from xT) ----
    const float* xp = xT + ((long)b * 21 + c) * 15000L + 32 * t0;
    for (int i = tid; i < L0T; i += 256) A[i] = xp[i];
    __syncthreads();

    // One K=7 stage: nch channels, pair-of-outputs per thread iteration.
    // Wave-uniform channel -> scalar weight loads. Reads are 3x ds_read_b128
    // at 16B lane stride (conflict-free); garbage in pads only feeds the
    // masked odd output of the final pair.
    auto convK7 = [&](const float* SIN, int sstride, bool from_x,
                      float* SOUT, int ostride,
                      const float* wg, const float* bg, int wbase,
                      int nch, int pairs, int Lout, bool b64st) {
        for (int it = 0; it < (nch >> 2); ++it) {
            const int chg = __builtin_amdgcn_readfirstlane((it << 2) + wq);
            const float* wp = wg + (size_t)(wbase + chg) * 7;
            const float W0 = wp[0], Wa = wp[1], Wb = wp[2], Wc = wp[3],
                        Wd = wp[4], We = wp[5], Wf = wp[6];
            const float bb = bg[wbase + chg];
            const float* sin_ch = SIN + (from_x ? 0 : (chg >> 1) * sstride);
            float* sout_ch = SOUT + chg * ostride;
            for (int j = lane; j < pairs; j += 64) {
                const int p = 2 * j;
                const float* s = sin_ch + p * 2;
                const float4 u0 = *(const float4*)(s);
                const float4 u1 = *(const float4*)(s + 4);
                const float4 u2 = *(const float4*)(s + 8);
                float o0 = bb, o1 = bb;
                o0 = fmaf(W0, u0.x, o0); o0 = fmaf(Wa, u0.y, o0); o0 = fmaf(Wb, u0.z, o0);
                o0 = fmaf(Wc, u0.w, o0); o0 = fmaf(Wd, u1.x, o0); o0 = fmaf(We, u1.y, o0);
                o0 = fmaf(Wf, u1.z, o0);
                o1 = fmaf(W0, u0.z, o1); o1 = fmaf(Wa, u0.w, o1); o1 = fmaf(Wb, u1.x, o1);
                o1 = fmaf(Wc, u1.y, o1); o1 = fmaf(Wd, u1.z, o1); o1 = fmaf(We, u1.w, o1);
                o1 = fmaf(Wf, u2.x, o1);
                if (p + 1 < Lout) {
                    if (b64st) *(float2*)(sout_ch + p) = make_float2(o0, o1);
                    else       { sout_ch[p] = o0; sout_ch[p + 1] = o1; }
                } else {
                    sout_ch[p] = o0;
                }
            }
        }
    };

    convK7(A, 0,   true,  B, SS1, w1, b1, 8 * c,  8,  382, L1T, true);
    __syncthreads();
    convK7(B, SS1, false, A, SS2, w2, b2, 16 * c, 16, 190, L2T, true);
    __syncthreads();
    convK7(A, SS2, false, B, SS3, w3, b3, 32 * c, 32, 94,  L3T, true);
    __syncthreads();
    convK7(B, SS3, false, A, SS4, w4, b4, 64 * c, 64, 46,  L4T, false);
    __syncthreads();

    // ---- stage 5 (K=9) -> global embT [b][t][2688], coalesced writes ----
    {
        const int ch5 = tid & 127;
        const int th  = tid >> 7;
        const float* wp = w5 + (size_t)(128 * c + ch5) * 9;
        float V[9];
#pragma unroll
        for (int k = 0; k < 9; ++k) V[k] = wp[k];
        const float bb = b5[128 * c + ch5];
        const float* s4ch = A + (ch5 >> 1) * SS4;
        float* obase = embT + ((long)(b * TR + t0)) * C5 + 128 * c + ch5;
#pragma unroll
        for (int i = 0; i < 21; ++i) {
            const int tl = th + 2 * i;          // 0..41
            const float* sp = s4ch + 2 * tl;
            float acc = bb;
#pragma unroll
            for (int k = 0; k < 9; ++k) acc = fmaf(V[k], sp[k], acc);
            obase[(long)tl * C5] = acc;
        }
    }
}

// Gather che + precompute cheC / cheLN (both straight from table; independent).
__global__ void prep_kernel(const float* __restrict__ table, const int* __restrict__ chv,
                            const float* __restrict__ mw1, const float* __restrict__ mw2,
                            float* __restrict__ che, float* __restrict__ cheC,
                            float* __restrict__ cheLN)
{
    const int b = blockIdx.x;
    const int m = threadIdx.x;   // 0..127

    for (int idx = m; idx < 21 * 512; idx += 128) {
        int k = idx >> 9, j = idx & 511;
        che[b * 10752 + idx] = table[chv[b * 21 + k] * 512 + j];
    }

    float W1[4], W2[4], c2[10];
#pragma unroll
    for (int q = 0; q < 4; ++q) { W1[q] = mw1[q]; W2[q] = mw2[q]; }
    composite10(W2, W1, c2);

    for (int k = 0; k < 21; ++k) {
        const float* cb = table + (long)chv[b * 21 + k] * 512;
        float acc = 0.f;
        if (m == 0) {
#pragma unroll
            for (int r = 3; r < 10; ++r) acc = fmaf(c2[r], cb[r - 3], acc);
        } else if (m == 127) {
#pragma unroll
            for (int r = 0; r < 7; ++r) acc = fmaf(c2[r], cb[505 + r], acc);
        } else {
            int j0 = 4 * m - 3;
#pragma unroll
            for (int r = 0; r < 10; ++r) acc = fmaf(c2[r], cb[j0 + r], acc);
        }
        cheC[b * 2688 + k * 128 + m] = acc;
    }
    if (m < 21) {
        int k = m;
        const float* cb = table + (long)chv[b * 21 + k] * 512;
        float l = 0.f, n = 0.f;
#pragma unroll
        for (int r = 0; r < 3; ++r)  l = fmaf(c2[r], cb[509 + r], l);
#pragma unroll
        for (int r = 7; r < 10; ++r) n = fmaf(c2[r], cb[r - 7], n);
        cheLN[b * 42 + k]      = l;
        cheLN[b * 42 + 21 + k] = n;
    }
}

// Fused einsum+conv-chain (unchanged from R3).
__global__ __launch_bounds__(256)
void fused_embed_kernel(const float* __restrict__ embT,   // [B][Tr][2688]
                        const float* __restrict__ cheC,   // [B][21][128]
                        const float* __restrict__ cheLN,  // [B][2][21]
                        const float* __restrict__ che,    // [B][21][512]
                        const float* __restrict__ mw1, const float* __restrict__ mb1,
                        const float* __restrict__ mw2, const float* __restrict__ mb2,
                        const float* __restrict__ mw3, const float* __restrict__ mb3,
                        const float* __restrict__ mw4, const float* __restrict__ mb4,
                        float* __restrict__ out)
{
    __shared__ float s_g2[8336];

    const int half = blockIdx.x;
    const int t    = blockIdx.y;
    const int b    = blockIdx.z;
    const int tid  = threadIdx.x;
    const int m    = tid & 127;
    const int h    = tid >> 7;
    const int ibase = half * 63;

    if (tid < 16) s_g2[(tid < 4) ? tid : (8320 + tid)] = 0.f;

    float W1[4], W2[4], W3[4], W4[4];
#pragma unroll
    for (int q = 0; q < 4; ++q) { W1[q] = mw1[q]; W2[q] = mw2[q]; W3[q] = mw3[q]; W4[q] = mw4[q]; }
    const float B1 = mb1[0], B2 = mb2[0], B3 = mb3[0], B4 = mb4[0];
    const float Bc = B2 + B1 * (W2[0] + W2[1] + W2[2] + W2[3]);

    const float* ccp = cheC + b * 2688 + m;
    float cc[21];
#pragma unroll
    for (int k = 0; k < 21; ++k) cc[k] = ccp[k * 128];

    const float* ebase = embT + ((long)(b * TR + t)) * C5;

    const int s0 = h ? 33 : 0;
    const int s1 = h ? 65 : 33;
#pragma unroll 2
    for (int s = s0; s < s1; ++s) {
        int i = __builtin_amdgcn_readfirstlane(ibase + s);
        const float* er = ebase + i * 21;
        float z = Bc;
#pragma unroll
        for (int k = 0; k < 21; ++k) z = fmaf(er[k], cc[k], z);
        float gz = gelu_exact(z);
        bool bnd = (m == 0) || (m == 127);
        s_g2[4 + s * 128 + m] = bnd ? z : gz;
    }
    __syncthreads();

    if (tid < 130) {
        const int ir   = tid >> 1;
        const int side = tid & 1;
        const int i    = ibase + ir;
        const int slot = 4 + ir * 128 + (side ? 127 : 0);
        float corr = 0.f;
        if (side == 0) {
            if (i == 0) {
                float w0 = 0.f;
                const float* cb = che + b * 21 * 512;
#pragma unroll
                for (int k = 0; k < 21; ++k) w0 = fmaf(ebase[k], cb[k * 512], w0);
                corr = -W2[0] * (B1 + W1[3] * w0);
            } else {
                const float* ep = ebase + (i - 1) * 21;
                const float* cl = cheLN + b * 42;
#pragma unroll
                for (int k = 0; k < 21; ++k) corr = fmaf(ep[k], cl[k], corr);
            }
        } else {
            if (i == 127) {
                float wl = 0.f;
                const float* cb = che + b * 21 * 512 + 511;
                const float* ep = ebase + 127 * 21;
#pragma unroll
                for (int k = 0; k < 21; ++k) wl = fmaf(ep[k], cb[k * 512], wl);
                corr = -W2[3] * (B1 + W1[0] * wl);
            } else {
                const float* ep = ebase + (i + 1) * 21;
                const float* cn = cheLN + b * 42 + 21;
#pragma unroll
                for (int k = 0; k < 21; ++k) corr = fmaf(ep[k], cn[k], corr);
            }
        }
        s_g2[slot] = gelu_exact(s_g2[slot] + corr);
    }
    __syncthreads();

    float c4[10];
    composite10(W4, W3, c4);
    const float Bc2 = B4 + B3 * (W4[0] + W4[1] + W4[2] + W4[3]);
    float* orow = out + ((long)(b * TR + t)) * OUTROW;
#pragma unroll
    for (int s = 0; s < 8; ++s) {
        const int p    = half * 2048 + tid + 256 * s;
        const int idx0 = 4 * p - (half ? 8064 : 0);
        const float4 v0 = *(const float4*)&s_g2[idx0];
        const float4 v1 = *(const float4*)&s_g2[idx0 + 4];
        const float4 v2 = *(const float4*)&s_g2[idx0 + 8];
        const float buf[12] = { v0.x, v0.y, v0.z, v0.w,
                                v1.x, v1.y, v1.z, v1.w,
                                v2.x, v2.y, v2.z, v2.w };
        float z = Bc2;
#pragma unroll
        for (int r = 0; r < 10; ++r) z = fmaf(c4[r], buf[r + 1], z);
        if (p == 0)    z -= W4[0] * (B3 + W3[3] * s_g2[4]);
        if (p == 4095) z -= W4[3] * (B3 + W3[0] * s_g2[8323]);
        orow[p] = gelu_exact(z);
    }
}

extern "C" void kernel_launch(void* const* d_in, const int* in_sizes, int n_in,
                              void* d_out, int out_size, void* d_ws, size_t ws_size,
                              hipStream_t stream)
{
    const float* x   = (const float*)d_in[0];
    const int*   chv = (const int*)d_in[1];
    const float* w1  = (const float*)d_in[2];  const float* b1 = (const float*)d_in[3];
    const float* w2  = (const float*)d_in[4];  const float* b2 = (const float*)d_in[5];
    const float* w3  = (const float*)d_in[6];  const float* b3 = (const float*)d_in[7];
    const float* w4  = (const float*)d_in[8];  const float* b4 = (const float*)d_in[9];
    const float* w5  = (const float*)d_in[10]; const float* b5 = (const float*)d_in[11];
    const float* tab = (const float*)d_in[12];
    const float* mw1 = (const float*)d_in[13]; const float* mb1 = (const float*)d_in[14];
    const float* mw2 = (const float*)d_in[15]; const float* mb2 = (const float*)d_in[16];
    const float* mw3 = (const float*)d_in[17]; const float* mb3 = (const float*)d_in[18];
    const float* mw4 = (const float*)d_in[19]; const float* mb4 = (const float*)d_in[20];
    float* outp = (float*)d_out;

    float* ws    = (float*)d_ws;
    float* xT    = ws;                 // 630,000 floats
    float* embT  = ws + 630000;        // 2,483,712 floats
    float* che   = ws + 3113712;       // 21,504
    float* cheC  = ws + 3135216;       // 5,376
    float* cheLN = ws + 3140592;       // 84

    {
        dim3 grid((15000 + 255) / 256, NB);
        transpose_x_kernel<<<grid, 256, 0, stream>>>(x, xT);
    }

    {
        dim3 grid(11, 21, NB);   // tile, c, b
        conv_stack_kernel<<<grid, 256, 0, stream>>>(xT, w1, b1, w2, b2, w3, b3,
                                                    w4, b4, w5, b5, embT);
    }

    prep_kernel<<<NB, 128, 0, stream>>>(tab, chv, mw1, mw2, che, cheC, cheLN);

    dim3 grid(2, TR, NB);  // half, t, b
    fused_embed_kernel<<<grid, 256, 0, stream>>>(embT, cheC, cheLN, che,
                                                 mw1, mb1, mw2, mb2, mw3, mb3, mw4, mb4,
                                                 outp);
}

// Round 5
// 68.548 us; speedup vs baseline: 6.0036x; 1.3893x over previous
//
#include <hip/hip_runtime.h>
#include <math.h>

// ---------------------------------------------------------------------------
// InputEmbedder. Sizes: B=2, T=15000, CHNLS=21, HIDDEN=128, Tr=462
// R5: fused kernel inverted — thread owns emb ROW (VGPR), cheCT is the
// wave-uniform SGPR operand; emb row staged to LDS in one coalesced burst.
// s_g2 float4-granular XOR swizzle. conv_stack retiled T5=21 (924 blocks).
// ---------------------------------------------------------------------------

#define NB 2
#define TR 462
#define C5 2688          // HIDDEN*CHNLS
#define OUTROW 4096      // HIDDEN*32

// conv-stack tiling: 22 tiles of T5=21 stage-5 outputs (462 = 22*21)
#define T5  21
#define L0T 859          // 32*T5 + 187
#define L1T 427
#define L2T 211
#define L3T 103
#define L4T 49
#define SS1 432          // >= max read idx+1 (431), mult of 4
#define SS2 216
#define SS3 108
#define SS4 49           // odd -> stage-5 reads conflict-free

__device__ __forceinline__ float gelu_exact(float x) {
    return 0.5f * x * (1.0f + erff(x * 0.7071067811865476f));
}

// float4-granularity XOR swizzle for s_g2 (breaks stride-128 bank aliasing)
__device__ __forceinline__ int swz(int a) { return a ^ (((a >> 7) & 7) << 2); }

// c[r] = sum_{2p+q=r, p,q in [0,4)} A[p]*B[q]
__device__ __forceinline__ void composite10(const float* A, const float* Bv, float* c) {
#pragma unroll
    for (int r = 0; r < 10; ++r) {
        float acc = 0.f;
#pragma unroll
        for (int p = 0; p < 4; ++p) {
            int q = r - 2 * p;
            if (q >= 0 && q < 4) acc = fmaf(A[p], Bv[q], acc);
        }
        c[r] = acc;
    }
}

// Transpose x [B][15000][21] -> xT [B][21][15000]
__global__ void transpose_x_kernel(const float* __restrict__ in, float* __restrict__ out)
{
    __shared__ float s[21 * 257];
    const int b   = blockIdx.y;
    const int t0  = blockIdx.x * 256;
    const int tid = threadIdx.x;
    const float* src = in + (long)b * 315000L + (long)t0 * 21L;
    const int limit = 315000 - t0 * 21;
#pragma unroll
    for (int j = 0; j < 21; ++j) {
        int f = tid + j * 256;
        if (f < limit) {
            int t = f / 21, c = f - t * 21;
            s[c * 257 + t] = src[f];
        }
    }
    __syncthreads();
    float* dst = out + (long)b * 315000L + t0;
    if (t0 + tid < 15000) {
#pragma unroll
        for (int c = 0; c < 21; ++c)
            dst[c * 15000 + tid] = s[c * 257 + tid];
    }
}

// All 5 depthwise stages for one (b, orig-channel c, time tile) in LDS.
__global__ __launch_bounds__(256, 5)
void conv_stack_kernel(const float* __restrict__ xT,
                       const float* __restrict__ w1, const float* __restrict__ b1,
                       const float* __restrict__ w2, const float* __restrict__ b2,
                       const float* __restrict__ w3, const float* __restrict__ b3,
                       const float* __restrict__ w4, const float* __restrict__ b4,
                       const float* __restrict__ w5, const float* __restrict__ b5,
                       float* __restrict__ embT)
{
    __shared__ __align__(16) float A[3456];   // x(859) -> s2(16x216) -> s4(64x49)
    __shared__ __align__(16) float B[3456];   // s1(8x432) -> s3(32x108)
    const int tile = blockIdx.x;
    const int c    = blockIdx.y;
    const int b    = blockIdx.z;
    const int tid  = threadIdx.x;
    const int lane = tid & 63;
    const int wq   = tid >> 6;        // 0..3
    const int t0   = tile * T5;

    const float* xp = xT + ((long)b * 21 + c) * 15000L + 32 * t0;
    for (int i = tid; i < L0T; i += 256) A[i] = xp[i];
    __syncthreads();

    auto convK7 = [&](const float* SIN, int sstride, bool from_x,
                      float* SOUT, int ostride,
                      const float* wg, const float* bg, int wbase,
                      int nch, int pairs, int Lout, bool b64st) {
        for (int it = 0; it < (nch >> 2); ++it) {
            const int chg = __builtin_amdgcn_readfirstlane((it << 2) + wq);
            const float* wp = wg + (size_t)(wbase + chg) * 7;
            const float W0 = wp[0], Wa = wp[1], Wb = wp[2], Wc = wp[3],
                        Wd = wp[4], We = wp[5], Wf = wp[6];
            const float bb = bg[wbase + chg];
            const float* sin_ch = SIN + (from_x ? 0 : (chg >> 1) * sstride);
            float* sout_ch = SOUT + chg * ostride;
            for (int j = lane; j < pairs; j += 64) {
                const int p = 2 * j;
                const float* s = sin_ch + p * 2;
                const float4 u0 = *(const float4*)(s);
                const float4 u1 = *(const float4*)(s + 4);
                const float4 u2 = *(const float4*)(s + 8);
                float o0 = bb, o1 = bb;
                o0 = fmaf(W0, u0.x, o0); o0 = fmaf(Wa, u0.y, o0); o0 = fmaf(Wb, u0.z, o0);
                o0 = fmaf(Wc, u0.w, o0); o0 = fmaf(Wd, u1.x, o0); o0 = fmaf(We, u1.y, o0);
                o0 = fmaf(Wf, u1.z, o0);
                o1 = fmaf(W0, u0.z, o1); o1 = fmaf(Wa, u0.w, o1); o1 = fmaf(Wb, u1.x, o1);
                o1 = fmaf(Wc, u1.y, o1); o1 = fmaf(Wd, u1.z, o1); o1 = fmaf(We, u1.w, o1);
                o1 = fmaf(Wf, u2.x, o1);
                if (p + 1 < Lout) {
                    if (b64st) *(float2*)(sout_ch + p) = make_float2(o0, o1);
                    else       { sout_ch[p] = o0; sout_ch[p + 1] = o1; }
                } else {
                    sout_ch[p] = o0;
                }
            }
        }
    };

    convK7(A, 0,   true,  B, SS1, w1, b1, 8 * c,  8,  214, L1T, true);
    __syncthreads();
    convK7(B, SS1, false, A, SS2, w2, b2, 16 * c, 16, 106, L2T, true);
    __syncthreads();
    convK7(A, SS2, false, B, SS3, w3, b3, 32 * c, 32, 52,  L3T, true);
    __syncthreads();
    convK7(B, SS3, false, A, SS4, w4, b4, 64 * c, 64, 25,  L4T, false);
    __syncthreads();

    // stage 5 (K=9) -> embT [b][t][2688], coalesced writes
    {
        const int ch5 = tid & 127;
        const int th  = tid >> 7;
        const float* wp = w5 + (size_t)(128 * c + ch5) * 9;
        float V[9];
#pragma unroll
        for (int k = 0; k < 9; ++k) V[k] = wp[k];
        const float bb = b5[128 * c + ch5];
        const float* s4ch = A + (ch5 >> 1) * SS4;
        float* obase = embT + ((long)(b * TR + t0)) * C5 + 128 * c + ch5;
#pragma unroll
        for (int iu = 0; iu < 11; ++iu) {
            const int tl = th + 2 * iu;
            if (tl < T5) {
                const float* sp = s4ch + 2 * tl;
                float acc = bb;
#pragma unroll
                for (int k = 0; k < 9; ++k) acc = fmaf(V[k], sp[k], acc);
                obase[(long)tl * C5] = acc;
            }
        }
    }
}

// Precompute cheCT[b][m][k] (m-major!) and cheLN4[b][{L,N,V0,V511}][k].
__global__ void prep_kernel(const float* __restrict__ table, const int* __restrict__ chv,
                            const float* __restrict__ mw1, const float* __restrict__ mw2,
                            float* __restrict__ cheCT, float* __restrict__ cheLN4)
{
    const int b = blockIdx.x;
    const int m = threadIdx.x;   // 0..127
    float W1[4], W2[4], c2[10];
#pragma unroll
    for (int q = 0; q < 4; ++q) { W1[q] = mw1[q]; W2[q] = mw2[q]; }
    composite10(W2, W1, c2);

    for (int k = 0; k < 21; ++k) {
        const float* cb = table + (long)chv[b * 21 + k] * 512;
        float acc = 0.f;
        if (m == 0) {
#pragma unroll
            for (int r = 3; r < 10; ++r) acc = fmaf(c2[r], cb[r - 3], acc);
        } else if (m == 127) {
#pragma unroll
            for (int r = 0; r < 7; ++r) acc = fmaf(c2[r], cb[505 + r], acc);
        } else {
            int j0 = 4 * m - 3;
#pragma unroll
            for (int r = 0; r < 10; ++r) acc = fmaf(c2[r], cb[j0 + r], acc);
        }
        cheCT[b * 2688 + m * 21 + k] = acc;
    }
    if (m < 21) {
        const float* cb = table + (long)chv[b * 21 + m] * 512;
        float l = 0.f, n = 0.f;
#pragma unroll
        for (int r = 0; r < 3; ++r)  l = fmaf(c2[r], cb[509 + r], l);
#pragma unroll
        for (int r = 7; r < 10; ++r) n = fmaf(c2[r], cb[r - 7], n);
        cheLN4[b * 84 + m]      = l;        // L
        cheLN4[b * 84 + 21 + m] = n;        // N
        cheLN4[b * 84 + 42 + m] = cb[0];    // V0
        cheLN4[b * 84 + 63 + m] = cb[511];  // V511
    }
}

// Fused einsum+tail-convs, one block per (b,t), 512 threads.
// thread: i = tid&127 (emb row in VGPRs), mq = tid>>7 (m-chunk of 32).
__global__ __launch_bounds__(512, 4)
void fused_embed_kernel(const float* __restrict__ embT,   // [B][Tr][2688]
                        const float* __restrict__ cheCT,  // [B][128][21]
                        const float* __restrict__ cheLN4, // [B][4][21]
                        const float* __restrict__ mw1, const float* __restrict__ mb1,
                        const float* __restrict__ mw2, const float* __restrict__ mb2,
                        const float* __restrict__ mw3, const float* __restrict__ mb3,
                        const float* __restrict__ mw4, const float* __restrict__ mb4,
                        float* __restrict__ out)
{
    __shared__ float s_g2[16400];   // slot = swz(4 + u), u in [0,16384); pads zero
    __shared__ float s_emb[2688];
    __shared__ float s_ln[84];

    const int t   = blockIdx.x;
    const int b   = blockIdx.y;
    const int tid = threadIdx.x;
    const int i   = tid & 127;
    const int mq  = __builtin_amdgcn_readfirstlane(tid >> 7);

    // one coalesced burst: emb row -> LDS
    const float* erow = embT + ((long)(b * TR + t)) * C5;
    for (int j = tid; j < 672; j += 512)
        *(float4*)&s_emb[j * 4] = ((const float4*)erow)[j];
    if (tid < 84) s_ln[tid] = cheLN4[b * 84 + tid];
    if (tid < 4)       s_g2[tid] = 0.f;
    else if (tid < 20) s_g2[16380 + tid] = 0.f;

    float W1[4], W2[4], W3[4], W4[4];
#pragma unroll
    for (int q = 0; q < 4; ++q) { W1[q] = mw1[q]; W2[q] = mw2[q]; W3[q] = mw3[q]; W4[q] = mw4[q]; }
    const float B1 = mb1[0], B2 = mb2[0], B3 = mb3[0], B4 = mb4[0];
    const float Bc = B2 + B1 * (W2[0] + W2[1] + W2[2] + W2[3]);

    __syncthreads();

    // emb row i -> registers (stride 21 coprime 32 banks: conflict-free)
    float er[21];
#pragma unroll
    for (int k = 0; k < 21; ++k) er[k] = s_emb[i * 21 + k];

    // ---- phase A: z2/g2 for 32 m per thread, 4 chains per float4 ----
    const float* cp = cheCT + (b * 128 + mq * 32) * 21;   // uniform -> s_load
#pragma unroll
    for (int mi4 = 0; mi4 < 8; ++mi4) {
        const int m0 = mq * 32 + mi4 * 4;
        const float* cc = cp + mi4 * 84;
        float z0 = Bc, z1 = Bc, z2 = Bc, z3 = Bc;
#pragma unroll
        for (int k = 0; k < 21; ++k) {
            const float e = er[k];
            z0 = fmaf(e, cc[k],      z0);
            z1 = fmaf(e, cc[21 + k], z1);
            z2 = fmaf(e, cc[42 + k], z2);
            z3 = fmaf(e, cc[63 + k], z3);
        }
        float4 q;
        q.x = (m0 == 0)       ? z0 : gelu_exact(z0);   // boundary: raw, fixed in A2
        q.y = gelu_exact(z1);
        q.z = gelu_exact(z2);
        q.w = (m0 + 3 == 127) ? z3 : gelu_exact(z3);
        *(float4*)&s_g2[swz(4 + i * 128 + m0)] = q;
    }
    __syncthreads();

    // ---- phase A2: boundary-column corrections (m=0 / m=127 per row) ----
    if (tid < 256) {
        const int ir   = tid >> 1;
        const int side = tid & 1;
        const int slot = swz(4 + ir * 128 + (side ? 127 : 0));
        float corr = 0.f;
        if (side == 0) {
            if (ir == 0) {
                float w0 = 0.f;
#pragma unroll
                for (int k = 0; k < 21; ++k) w0 = fmaf(s_emb[k], s_ln[42 + k], w0);
                corr = -W2[0] * (B1 + W1[3] * w0);
            } else {
#pragma unroll
                for (int k = 0; k < 21; ++k) corr = fmaf(s_emb[(ir - 1) * 21 + k], s_ln[k], corr);
            }
        } else {
            if (ir == 127) {
                float wl = 0.f;
#pragma unroll
                for (int k = 0; k < 21; ++k) wl = fmaf(s_emb[127 * 21 + k], s_ln[63 + k], wl);
                corr = -W2[3] * (B1 + W1[0] * wl);
            } else {
#pragma unroll
                for (int k = 0; k < 21; ++k) corr = fmaf(s_emb[(ir + 1) * 21 + k], s_ln[21 + k], corr);
            }
        }
        s_g2[slot] = gelu_exact(s_g2[slot] + corr);
    }
    __syncthreads();

    // ---- phase B: composite conv3∘conv4, gelu, store ----
    float c4[10];
    composite10(W4, W3, c4);
    const float Bc2 = B4 + B3 * (W4[0] + W4[1] + W4[2] + W4[3]);
    float* orow = out + ((long)(b * TR + t)) * OUTROW;
#pragma unroll
    for (int s = 0; s < 8; ++s) {
        const int p  = tid + 512 * s;
        const int a0 = 4 * p;
        const float4 v0 = *(const float4*)&s_g2[swz(a0)];
        const float4 v1 = *(const float4*)&s_g2[swz(a0 + 4)];
        const float4 v2 = *(const float4*)&s_g2[swz(a0 + 8)];
        const float buf[12] = { v0.x, v0.y, v0.z, v0.w,
                                v1.x, v1.y, v1.z, v1.w,
                                v2.x, v2.y, v2.z, v2.w };
        float z = Bc2;
#pragma unroll
        for (int r = 0; r < 10; ++r) z = fmaf(c4[r], buf[r + 1], z);
        if (p == 0)    z -= W4[0] * (B3 + W3[3] * s_g2[swz(4)]);
        if (p == 4095) z -= W4[3] * (B3 + W3[0] * s_g2[swz(16387)]);
        orow[p] = gelu_exact(z);
    }
}

extern "C" void kernel_launch(void* const* d_in, const int* in_sizes, int n_in,
                              void* d_out, int out_size, void* d_ws, size_t ws_size,
                              hipStream_t stream)
{
    const float* x   = (const float*)d_in[0];
    const int*   chv = (const int*)d_in[1];
    const float* w1  = (const float*)d_in[2];  const float* b1 = (const float*)d_in[3];
    const float* w2  = (const float*)d_in[4];  const float* b2 = (const float*)d_in[5];
    const float* w3  = (const float*)d_in[6];  const float* b3 = (const float*)d_in[7];
    const float* w4  = (const float*)d_in[8];  const float* b4 = (const float*)d_in[9];
    const float* w5  = (const float*)d_in[10]; const float* b5 = (const float*)d_in[11];
    const float* tab = (const float*)d_in[12];
    const float* mw1 = (const float*)d_in[13]; const float* mb1 = (const float*)d_in[14];
    const float* mw2 = (const float*)d_in[15]; const float* mb2 = (const float*)d_in[16];
    const float* mw3 = (const float*)d_in[17]; const float* mb3 = (const float*)d_in[18];
    const float* mw4 = (const float*)d_in[19]; const float* mb4 = (const float*)d_in[20];
    float* outp = (float*)d_out;

    float* ws     = (float*)d_ws;
    float* xT     = ws;                 // 630,000 floats
    float* embT   = ws + 630000;        // 2,483,712 floats (16B aligned)
    float* cheCT  = ws + 3113712;       // 5,376
    float* cheLN4 = ws + 3119088;       // 168

    {
        dim3 grid((15000 + 255) / 256, NB);
        transpose_x_kernel<<<grid, 256, 0, stream>>>(x, xT);
    }
    {
        dim3 grid(22, 21, NB);   // tile, c, b
        conv_stack_kernel<<<grid, 256, 0, stream>>>(xT, w1, b1, w2, b2, w3, b3,
                                                    w4, b4, w5, b5, embT);
    }
    prep_kernel<<<NB, 128, 0, stream>>>(tab, chv, mw1, mw2, cheCT, cheLN4);

    dim3 grid(TR, NB);  // t, b
    fused_embed_kernel<<<grid, 512, 0, stream>>>(embT, cheCT, cheLN4,
                                                 mw1, mb1, mw2, mb2, mw3, mb3, mw4, mb4,
                                                 outp);
}